// Round 25
// baseline (1240.654 us; speedup 1.0000x reference)
//
#include <hip/hip_runtime.h>
#include <cstdio>
#include <type_traits>

#define NQ 10000
#define NT 50000
#define NA 50000
#define E_GR 50000
#define E_LT 50000
#define E_SIM 80000
#define E_COMP 100000
#define E_GEN 50000
#define NEG_SLOPE 0.2f

// Concatenated CSR tables (compile-time). Rel order: gr, rgr, rlt, sim, comp, lt
#define NDTOT 220000
#define NSTOT 220000
#define ETOT  390000
__device__ __constant__ const int c_degOff[7]  = {0, 50000, 60000, 110000, 120000, 170000, 220000};
__device__ __constant__ const int c_sOff[7]    = {0, 10000, 60000, 110000, 120000, 170000, 220000};
__device__ __constant__ const int c_eOff[7]    = {0, 50000, 100000, 150000, 240000, 340000, 390000};
__device__ __constant__ const int c_nb[6]      = {49, 10, 49, 10, 49, 49};
__device__ __constant__ const int c_nbOff[7]   = {0, 49, 59, 108, 118, 167, 216};
__device__ __constant__ const int c_snb[6]     = {10, 49, 49, 10, 49, 49};
__device__ __constant__ const int c_snbOff[7]  = {0, 10, 59, 108, 118, 167, 216};

typedef unsigned short bf16_t;
typedef unsigned int u32;
typedef __attribute__((ext_vector_type(8))) short short8v;
typedef __attribute__((ext_vector_type(4))) float f32x4;

__device__ __forceinline__ float bf2f(u32 bits) { return __uint_as_float(bits << 16); }
__device__ __forceinline__ u32 f2bf(float f) {
  u32 u = __float_as_uint(f);
  return (u + 0x7FFFu + ((u >> 16) & 1u)) >> 16;   // RTNE
}
__device__ __forceinline__ u32 pack2(float a, float b) { return f2bf(a) | (f2bf(b) << 16); }
__device__ __forceinline__ void unpack8(uint4 u, float* f) {
  f[0] = bf2f(u.x & 0xffffu); f[1] = bf2f(u.x >> 16);
  f[2] = bf2f(u.y & 0xffffu); f[3] = bf2f(u.y >> 16);
  f[4] = bf2f(u.z & 0xffffu); f[5] = bf2f(u.z >> 16);
  f[6] = bf2f(u.w & 0xffffu); f[7] = bf2f(u.w >> 16);
}

// async global->LDS, 16B per lane; LDS dest = wave-uniform base + lane*16.
__device__ __forceinline__ void gload16(const void* g, void* l) {
  __builtin_amdgcn_global_load_lds(
      (const __attribute__((address_space(1))) void*)g,
      (__attribute__((address_space(3))) void*)l, 16, 0, 0);
}

// GEMM descriptor (per z-slice): C = A @ Bt^T (+bias | +=C), rows N (or *Nc),
// optional row-gather ridx, per-slice K.
struct GemmDesc {
  const bf16_t* A; const bf16_t* Bt; const float* bias; void* C;
  const int* ridx; int N; const int* Nc; int K;
};

// ---------------------------------------------------------------------------
// bgemmW: WIDE MFMA bf16 GEMM for M=512 (conv + input-proj hot path).
// Tile 128x512 (ncol=1 -> A panel read ONCE), 8 waves, per-wave 128x64 out
// (m201 per-wave geometry), acc[8][4] = 32 frags per wave -> 32 MFMA per
// 12 LDS b128 reads (-25% LDS/FLOP vs 4x4). Same proven schedule as bgemm:
// 3x40KB LDS rotation s%3 (1 block/CU), ONE barrier/step, counted vmcnt(5),
// both-sides octet XOR (rule #21), XCD-grouped band swizzle, dynamic Nc,
// ridx gather, N==0 -> uniform exit before any barrier. bf16 out + bias.
// ---------------------------------------------------------------------------
__global__ __launch_bounds__(512, 2) void bgemmW(
    GemmDesc d0, GemmDesc d1, GemmDesc d2, GemmDesc d3)
{
  __shared__ short lds[3][20480];   // [buf][A: 0..4096 | B: 4096..20480)
  const int z = blockIdx.z;
  GemmDesc d = (z == 3) ? d3 : (z == 2) ? d2 : (z == 1) ? d1 : d0;
  int N = d.Nc ? *d.Nc : d.N;
  const int K = d.K;

  const int tid = threadIdx.x;
  const int nband = (N + 127) >> 7;
  int lin = blockIdx.y;
  if (lin >= nband) return;          // uniform exit, before barriers

  int band;
  const int full = (nband >> 3) * 8;
  if (lin < full) { int g = lin >> 3, x = lin & 7; band = x + 8 * g; }
  else            band = lin;        // tail bands identity
  const int bm = band * 128;

  const int lane = tid & 63;
  const int w = tid >> 6;            // 0..7: col-wave (cols [w*64, w*64+64))
  const int fr = lane & 15, fg = lane >> 4;

  const int kg = (((tid & 3) ^ ((tid >> 3) & 3)) << 3);
  const int rr = tid >> 2;           // 0..127
  int ra = min(bm + rr, N - 1);
  const bf16_t* gA0 = d.A + (size_t)(d.ridx ? d.ridx[ra] : ra) * K + kg;
  const bf16_t* gB0 = d.Bt + (size_t)(rr)       * K + kg;
  const bf16_t* gB1 = d.Bt + (size_t)(128 + rr) * K + kg;
  const bf16_t* gB2 = d.Bt + (size_t)(256 + rr) * K + kg;
  const bf16_t* gB3 = d.Bt + (size_t)(384 + rr) * K + kg;
  const int wb = w << 9;             // 512 shorts = 1KB per wave

  f32x4 acc[8][4];
#pragma unroll
  for (int i = 0; i < 8; ++i)
#pragma unroll
    for (int j = 0; j < 4; ++j) acc[i][j] = (f32x4){0.f, 0.f, 0.f, 0.f};

  auto stage = [&](int buf, int k0) {
    short* base = &lds[buf][0];
    gload16(gA0 + k0, base + wb);
    gload16(gB0 + k0, base + 4096 + wb);
    gload16(gB1 + k0, base + 8192 + wb);
    gload16(gB2 + k0, base + 12288 + wb);
    gload16(gB3 + k0, base + 16384 + wb);
  };

  const int nsteps = K >> 5;
  stage(0, 0);
  const int co = (fg ^ ((fr >> 1) & 3)) << 3;
  for (int s = 0; s < nsteps; ++s) {
    const int cur = s % 3;
    if (s + 1 < nsteps) {
      stage((s + 1) % 3, (s + 1) << 5);
      asm volatile("s_waitcnt vmcnt(5)" ::: "memory");
    } else {
      asm volatile("s_waitcnt vmcnt(0)" ::: "memory");
    }
    __builtin_amdgcn_s_barrier();
    asm volatile("" ::: "memory");
    const short* LA = &lds[cur][0];
    const short* LB = &lds[cur][4096];
    short8v b[4];
#pragma unroll
    for (int j = 0; j < 4; ++j) {
      int R = w * 64 + j * 16 + fr;
      b[j] = *(const short8v*)&LB[R * 32 + co];
    }
#pragma unroll
    for (int i = 0; i < 8; ++i) {
      int R = i * 16 + fr;
      short8v a = *(const short8v*)&LA[R * 32 + co];
#pragma unroll
      for (int j = 0; j < 4; ++j)
        acc[i][j] = __builtin_amdgcn_mfma_f32_16x16x32_bf16(b[j], a,
                                                            acc[i][j], 0, 0, 0);
    }
    asm volatile("" ::: "memory");
  }

  bf16_t* C = (bf16_t*)d.C;
  float4 bv[4];
#pragma unroll
  for (int j = 0; j < 4; ++j)
    bv[j] = *(const float4*)(d.bias + w * 64 + j * 16 + fg * 4);
#pragma unroll
  for (int i = 0; i < 8; ++i) {
    const int n = bm + i * 16 + fr;
    if (n >= N) continue;
#pragma unroll
    for (int j = 0; j < 4; ++j) {
      const int m0 = w * 64 + j * 16 + fg * 4;
      f32x4 v = acc[i][j];
      uint2 o;
      o.x = pack2(v[0] + bv[j].x, v[1] + bv[j].y);
      o.y = pack2(v[2] + bv[j].z, v[3] + bv[j].w);
      *(uint2*)(C + (size_t)n * 512 + m0) = o;
    }
  }
}

// ---------------------------------------------------------------------------
// MFMA bf16 GEMM, up to 4 z-slices (r12 banked structure) — retained for the
// head/prologue (M=256, K=64, f32 out, accumulate).
// ---------------------------------------------------------------------------
template <typename CT>
__global__ __launch_bounds__(512, 4) void bgemm(
    GemmDesc d0, GemmDesc d1, GemmDesc d2, GemmDesc d3, int M, int accumulate)
{
  __shared__ short lds[3][12288];   // [buf][A: 0..4095 | B: 4096..12287]
  const int z = blockIdx.z;
  GemmDesc d = (z == 3) ? d3 : (z == 2) ? d2 : (z == 1) ? d1 : d0;
  int N = d.Nc ? *d.Nc : d.N;
  const int K = d.K;

  const int tid = threadIdx.x;
  const int ncol = gridDim.x;
  const int nband = (N + 127) >> 7;
  int lin = blockIdx.y * ncol + blockIdx.x;
  if (lin >= ncol * nband) return;          // uniform exit, before barriers

  int band, col;
  const int full = (nband >> 3) * 8 * ncol;
  if (lin < full) {
    int g = lin >> 3, x = lin & 7;
    band = x + 8 * (g / ncol);
    col  = g % ncol;
  } else {
    int r = lin - full;
    band = (nband & ~7) + r / ncol;
    col  = r % ncol;
  }
  const int bm = band * 128, bn = col * 256;

  const int lane = tid & 63;
  const int w = tid >> 6;
  const int wr = w >> 2, wc = w & 3;
  const int fr = lane & 15, fg = lane >> 4;

  const int kg = (((tid & 3) ^ ((tid >> 3) & 3)) << 3);
  const int rr = tid >> 2;
  int ra = min(bm + rr, N - 1);
  const bf16_t* gA0 = d.A + (size_t)(d.ridx ? d.ridx[ra] : ra) * K + kg;
  const bf16_t* gB0 = d.Bt + (size_t)(bn + rr) * K + kg;
  const bf16_t* gB1 = d.Bt + (size_t)(bn + 128 + rr) * K + kg;
  const int wb = w << 9;

  f32x4 acc[4][4];
#pragma unroll
  for (int i = 0; i < 4; ++i)
#pragma unroll
    for (int j = 0; j < 4; ++j) acc[i][j] = (f32x4){0.f, 0.f, 0.f, 0.f};

  auto stage = [&](int buf, int k0) {
    short* base = &lds[buf][0];
    gload16(gA0 + k0, base + wb);
    gload16(gB0 + k0, base + 4096 + wb);
    gload16(gB1 + k0, base + 8192 + wb);
  };

  const int nsteps = K >> 5;
  stage(0, 0);
  const int co = (fg ^ ((fr >> 1) & 3)) << 3;
  for (int s = 0; s < nsteps; ++s) {
    const int cur = s % 3;
    if (s + 1 < nsteps) {
      stage((s + 1) % 3, (s + 1) << 5);
      asm volatile("s_waitcnt vmcnt(3)" ::: "memory");
    } else {
      asm volatile("s_waitcnt vmcnt(0)" ::: "memory");
    }
    __builtin_amdgcn_s_barrier();
    asm volatile("" ::: "memory");
    const short* LA = &lds[cur][0];
    const short* LB = &lds[cur][4096];
    short8v b[4];
#pragma unroll
    for (int j = 0; j < 4; ++j) {
      int R = wc * 64 + j * 16 + fr;
      b[j] = *(const short8v*)&LB[R * 32 + co];
    }
#pragma unroll
    for (int i = 0; i < 4; ++i) {
      int R = wr * 64 + i * 16 + fr;
      short8v a = *(const short8v*)&LA[R * 32 + co];
#pragma unroll
      for (int j = 0; j < 4; ++j)
        acc[i][j] = __builtin_amdgcn_mfma_f32_16x16x32_bf16(b[j], a,
                                                            acc[i][j], 0, 0, 0);
    }
    asm volatile("" ::: "memory");
  }

  CT* C = (CT*)d.C;
  float4 bv[4];
#pragma unroll
  for (int j = 0; j < 4; ++j) {
    bv[j] = make_float4(0.f, 0.f, 0.f, 0.f);
    if (!accumulate && d.bias)
      bv[j] = *(const float4*)(d.bias + bn + wc * 64 + j * 16 + fg * 4);
  }
#pragma unroll
  for (int i = 0; i < 4; ++i) {
    const int n = bm + wr * 64 + i * 16 + fr;
    if (n >= N) continue;
#pragma unroll
    for (int j = 0; j < 4; ++j) {
      const int m0 = bn + wc * 64 + j * 16 + fg * 4;
      f32x4 v = acc[i][j];
      if constexpr (std::is_same<CT, float>::value) {
        float* p = C + (size_t)n * M + m0;
        if (accumulate) {
          float4 o = *(float4*)p;
          o.x += v[0]; o.y += v[1]; o.z += v[2]; o.w += v[3];
          *(float4*)p = o;
        } else {
          *(float4*)p = make_float4(v[0] + bv[j].x, v[1] + bv[j].y,
                                    v[2] + bv[j].z, v[3] + bv[j].w);
        }
      } else {
        uint2 o;
        o.x = pack2(v[0] + bv[j].x, v[1] + bv[j].y);
        o.y = pack2(v[2] + bv[j].z, v[3] + bv[j].w);
        *(uint2*)(C + (size_t)n * M + m0) = o;
      }
    }
  }
}

// core transpose tile: fp32 W[K][M] slice -> bf16 Wt[M][K] slice
__device__ __forceinline__ void wT_tile(
    const float* __restrict__ W, bf16_t* __restrict__ Wt, int K, int M)
{
  __shared__ float sm[32][33];
  int mb = blockIdx.x * 32, kb = blockIdx.y * 32;
  int tx = threadIdx.x & 31, ty = threadIdx.x >> 5;
#pragma unroll
  for (int i = 0; i < 4; ++i)
    sm[ty + i * 8][tx] = W[(size_t)(kb + ty + i * 8) * M + mb + tx];
  __syncthreads();
#pragma unroll
  for (int i = 0; i < 4; ++i)
    Wt[(size_t)(mb + ty + i * 8) * K + kb + tx] = (bf16_t)f2bf(sm[tx][ty + i * 8]);
}

__global__ __launch_bounds__(256) void convert_wT(
    const float* __restrict__ W, bf16_t* __restrict__ Wt, int K, int M)
{
  wT_tile(W + (size_t)blockIdx.z * K * M, Wt + (size_t)blockIdx.z * K * M, K, M);
}
__global__ __launch_bounds__(256) void convert_wT24(
    const float* __restrict__ Wl, bf16_t* __restrict__ wl,
    const float* __restrict__ Wr, bf16_t* __restrict__ wr)
{
  int z = blockIdx.z;
  size_t o = (size_t)(z < 12 ? z : z - 12) * 512 * 512;
  if (z < 12) wT_tile(Wl + o, wl + o, 512, 512);
  else        wT_tile(Wr + o, wr + o, 512, 512);
}
__global__ __launch_bounds__(256) void convert_wT3(
    const float* __restrict__ W0, const float* __restrict__ W1,
    const float* __restrict__ W2, bf16_t* __restrict__ T0,
    bf16_t* __restrict__ T1, bf16_t* __restrict__ T2)
{
  int z = blockIdx.z;
  const float* W = z == 0 ? W0 : z == 1 ? W1 : W2;
  bf16_t* T = z == 0 ? T0 : z == 1 ? T1 : T2;
  wT_tile(W, T, 384, 512);
}
__global__ __launch_bounds__(256) void convert_wT4h(
    const float* __restrict__ qh, const float* __restrict__ rh,
    bf16_t* __restrict__ wqh, bf16_t* __restrict__ wrh)
{
  int z = blockIdx.z;
  if (z == 0) wT_tile(qh, wqh, 512, 256);
  else        wT_tile(rh + (size_t)(z - 1) * 512 * 256,
                      wrh + (size_t)(z - 1) * 256 * 512, 512, 256);
}

// flat fp32 -> bf16 cast (n4 float4s)
__global__ __launch_bounds__(256) void cast_flat(
    const float* __restrict__ in, bf16_t* __restrict__ out, int n4)
{
  int t = blockIdx.x * 256 + threadIdx.x;
  if (t >= n4) return;
  float4 v = ((const float4*)in)[t];
  uint2 o;
  o.x = pack2(v.x, v.y);
  o.y = pack2(v.z, v.w);
  ((uint2*)out)[t] = o;
}

// cvec[m] = sum_k afp_b2[k] * rh2[k][m]
__global__ __launch_bounds__(256) void fold_cvec(
    const float* __restrict__ b2, const float* __restrict__ rh2,
    float* __restrict__ cvec)
{
  int m = threadIdx.x;
  float s = 0.f;
  for (int k = 0; k < 512; ++k) s = fmaf(b2[k], rh2[(size_t)k * 256 + m], s);
  cvec[m] = s;
}

// fused input casts: xq->xqb, xt->xlb, xa->xrb (float4 granularity)
#define N4_XQ (NQ * 96)
#define N4_XT (NT * 96)
#define N4_XA (NA * 96)
__global__ __launch_bounds__(256) void cast3(
    const float* __restrict__ xq, const float* __restrict__ xt,
    const float* __restrict__ xa, bf16_t* __restrict__ xqb,
    bf16_t* __restrict__ xtb, bf16_t* __restrict__ xab)
{
  long g = (long)blockIdx.x * 256 + threadIdx.x;
  const float* in; bf16_t* out; long idx;
  if (g < N4_XQ)                { in = xq; out = xqb; idx = g; }
  else if (g < N4_XQ + N4_XT)   { in = xt; out = xtb; idx = g - N4_XQ; }
  else if (g < N4_XQ + N4_XT + N4_XA) { in = xa; out = xab; idx = g - N4_XQ - N4_XT; }
  else return;
  float4 v = ((const float4*)in)[idx];
  uint2 o;
  o.x = pack2(v.x, v.y);
  o.y = pack2(v.z, v.w);
  ((uint2*)out)[idx] = o;
}

__global__ __launch_bounds__(256) void combine_bias6(
    const float* __restrict__ cb, float* __restrict__ bcAll)
{
  int g = blockIdx.x * 256 + threadIdx.x;
  if (g >= 6 * 512) return;
  int row = g >> 9, j = g & 511;
  int l = row / 3, kind = row % 3;
  const float* b = cb + (size_t)l * 6 * 512;
  float v;
  if (kind == 0)      v = (b[0 * 512 + j] + b[3 * 512 + j] + b[5 * 512 + j]) / 3.f;
  else if (kind == 1) v = (b[1 * 512 + j] + b[4 * 512 + j]) * 0.5f;
  else                v = b[2 * 512 + j];
  bcAll[(size_t)row * 512 + j] = v;
}

// ---------------------------------------------------------------------------
// Fused CSR build + compactions (wide 3-phase scan; jobs batched per phase).
// ---------------------------------------------------------------------------
__device__ __forceinline__ int find_rel6(int g, const int* off) {
  int r = 0;
#pragma unroll
  for (int k = 1; k < 6; ++k) r += (g >= off[k]);
  return r;
}

__global__ __launch_bounds__(256) void hist6(
    const int* __restrict__ d0, const int* __restrict__ d1,
    const int* __restrict__ d2, const int* __restrict__ d3,
    const int* __restrict__ d4, const int* __restrict__ d5,
    const int* __restrict__ s0p, const int* __restrict__ s1p,
    const int* __restrict__ s2p, const int* __restrict__ s3p,
    const int* __restrict__ s4p, const int* __restrict__ s5p,
    int* __restrict__ degAll, int* __restrict__ sdegAll, int* __restrict__ pos)
{
  int g = blockIdx.x * 256 + threadIdx.x;
  if (g >= ETOT) return;
  int r = find_rel6(g, c_eOff);
  int le = g - c_eOff[r];
  const int* dp = r == 0 ? d0 : r == 1 ? d1 : r == 2 ? d2 : r == 3 ? d3
                : r == 4 ? d4 : d5;
  const int* sp = r == 0 ? s0p : r == 1 ? s1p : r == 2 ? s2p : r == 3 ? s3p
                : r == 4 ? s4p : s5p;
  pos[g] = atomicAdd(&degAll[c_degOff[r] + dp[le]], 1);
  atomicAdd(&sdegAll[c_sOff[r] + sp[le]], 1);
}

// phase 1: 648 blocks = job(3) x 216 relation-blocks; 1024 items each.
__global__ __launch_bounds__(256) void scan1All(
    const int* __restrict__ degAll, const int* __restrict__ sdegAll,
    int* __restrict__ startAll, int* __restrict__ cposAll,
    int* __restrict__ sposAll, int* __restrict__ bsumAll)
{
  __shared__ int sm[256];
  int j = blockIdx.x / 216, bb = blockIdx.x % 216;
  const int* nbOff = (j == 2) ? c_snbOff : c_nbOff;
  const int* dOff  = (j == 2) ? c_sOff : c_degOff;
  const int* in    = (j == 2) ? sdegAll : degAll;
  int* out = j == 0 ? startAll : j == 1 ? cposAll : sposAll;
  int r = 0;
#pragma unroll
  for (int k = 1; k < 6; ++k) r += (bb >= nbOff[k]);
  int lb = bb - nbOff[r];
  int base0 = dOff[r], n = dOff[r + 1] - base0;
  int t = threadIdx.x;
  int base = lb * 1024 + t * 4;
  int v[4], sum = 0;
#pragma unroll
  for (int k = 0; k < 4; ++k) {
    int raw = (base + k < n) ? in[base0 + base + k] : 0;
    v[k] = j == 0 ? raw : j == 1 ? (raw >= 2 ? 1 : 0) : (raw >= 1 ? 1 : 0);
    sum += v[k];
  }
  sm[t] = sum;
  __syncthreads();
  for (int off = 1; off < 256; off <<= 1) {
    int x = (t >= off) ? sm[t - off] : 0;
    __syncthreads();
    sm[t] += x;
    __syncthreads();
  }
  int run = (t > 0) ? sm[t - 1] : 0;
  if (t == 255) bsumAll[j * 384 + r * 64 + lb] = sm[255];
#pragma unroll
  for (int k = 0; k < 4; ++k) {
    if (base + k < n) out[base0 + base + k] = run;
    run += v[k];
  }
}

// phase 2: 18 blocks (job x rel), exclusive scan of block sums (<=64).
__global__ __launch_bounds__(64) void scan2All(
    int* __restrict__ bsumAll, int* __restrict__ ccount, int* __restrict__ scount)
{
  __shared__ int sm[64];
  int j = blockIdx.x / 6, r = blockIdx.x % 6;
  int nb = (j == 2) ? c_snb[r] : c_nb[r];
  int t = threadIdx.x;
  int v = (t < nb) ? bsumAll[j * 384 + r * 64 + t] : 0;
  sm[t] = v;
  __syncthreads();
  for (int off = 1; off < 64; off <<= 1) {
    int x = (t >= off) ? sm[t - off] : 0;
    __syncthreads();
    sm[t] += x;
    __syncthreads();
  }
  if (t < nb) bsumAll[j * 384 + r * 64 + t] = sm[t] - v;   // exclusive
  if (t == nb - 1) {
    if (j == 1) ccount[r] = sm[t];
    if (j == 2) scount[r] = sm[t];
  }
}

// phase 3: add block offsets; grid covers 3 x 220000.
__global__ __launch_bounds__(256) void scan3All(
    int* __restrict__ startAll, int* __restrict__ cposAll,
    int* __restrict__ sposAll, const int* __restrict__ bsumAll)
{
  int g = blockIdx.x * 256 + threadIdx.x;
  if (g >= 3 * NDTOT) return;
  int j = g / NDTOT, ln0 = g % NDTOT;
  const int* dOff = (j == 2) ? c_sOff : c_degOff;
  int* out = j == 0 ? startAll : j == 1 ? cposAll : sposAll;
  int r = find_rel6(ln0, dOff);
  int ln = ln0 - dOff[r];
  out[ln0] += bsumAll[j * 384 + r * 64 + (ln >> 10)];
}

__global__ __launch_bounds__(256) void scatter6(
    const int* __restrict__ d0, const int* __restrict__ d1,
    const int* __restrict__ d2, const int* __restrict__ d3,
    const int* __restrict__ d4, const int* __restrict__ d5,
    const int* __restrict__ s0p, const int* __restrict__ s1p,
    const int* __restrict__ s2p, const int* __restrict__ s3p,
    const int* __restrict__ s4p, const int* __restrict__ s5p,
    const int* __restrict__ startAll, const int* __restrict__ pos,
    const int* __restrict__ sposAll,
    int* __restrict__ eidxAll, int* __restrict__ srcCAll)
{
  int g = blockIdx.x * 256 + threadIdx.x;
  if (g >= ETOT) return;
  int r = find_rel6(g, c_eOff);
  int le = g - c_eOff[r];
  const int* dp = r == 0 ? d0 : r == 1 ? d1 : r == 2 ? d2 : r == 3 ? d3
                : r == 4 ? d4 : d5;
  const int* sp = r == 0 ? s0p : r == 1 ? s1p : r == 2 ? s2p : r == 3 ? s3p
                : r == 4 ? s4p : s5p;
  eidxAll[c_eOff[r] + startAll[c_degOff[r] + dp[le]] + pos[g]] = le;
  srcCAll[g] = sposAll[c_sOff[r] + sp[le]];
}

// one kernel for both compactions (dst deg>=2 then src deg>=1)
__global__ __launch_bounds__(256) void compactBoth(
    const int* __restrict__ degAll, const int* __restrict__ cposAll,
    int* __restrict__ cidxAll,
    const int* __restrict__ sdegAll, const int* __restrict__ sposAll,
    int* __restrict__ sidxAll)
{
  int g = blockIdx.x * 256 + threadIdx.x;
  if (g < NDTOT) {
    if (degAll[g] >= 2) {
      int r = find_rel6(g, c_degOff);
      cidxAll[c_degOff[r] + cposAll[g]] = g - c_degOff[r];
    }
  } else if (g < NDTOT + NSTOT) {
    int h = g - NDTOT;
    if (sdegAll[h] >= 1) {
      int r = find_rel6(h, c_sOff);
      sidxAll[c_sOff[r] + sposAll[h]] = h - c_sOff[r];
    }
  }
}

// ---------------------------------------------------------------------------
// Fused GATv2: one wave per dst node. deg==0 -> 0; deg==1 -> xl[srcC];
// deg>=2 reads compacted xr at cpos[d]. srcC pre-remapped. Edge pipelined.
// ---------------------------------------------------------------------------
__global__ __launch_bounds__(256) void gat_fused(
    const bf16_t* __restrict__ xl, const bf16_t* __restrict__ xr,
    const int* __restrict__ srcC, const int* __restrict__ start,
    const int* __restrict__ deg, const int* __restrict__ eidx,
    const int* __restrict__ cpos, const float* __restrict__ att,
    bf16_t* __restrict__ acc, int Nd, int accumulate,
    const float* __restrict__ bc, float inv_div)
{
  int d = blockIdx.x * 4 + (threadIdx.x >> 6);
  if (d >= Nd) return;
  int lane = threadIdx.x & 63;

  float acc8[8] = {0.f, 0.f, 0.f, 0.f, 0.f, 0.f, 0.f, 0.f};
  int n = deg[d], s0 = start[d];
  if (n == 1) {
    int s = srcC[eidx[s0]];
    unpack8(*(const uint4*)(xl + (size_t)s * 512 + lane * 8), acc8);
  } else if (n > 1) {
    float xrr[8];
    unpack8(*(const uint4*)(xr + (size_t)cpos[d] * 512 + lane * 8), xrr);
    float at[8];
    *(float4*)(at)     = *(const float4*)(att + lane * 8);
    *(float4*)(at + 4) = *(const float4*)(att + lane * 8 + 4);
    float den = 0.f;
    int sN = srcC[eidx[s0]];
    for (int i = 0; i < n; ++i) {
      int s = sN;
      if (i + 1 < n) sN = srcC[eidx[s0 + i + 1]];
      float f[8];
      unpack8(*(const uint4*)(xl + (size_t)s * 512 + lane * 8), f);
      float p = 0.f;
#pragma unroll
      for (int k = 0; k < 8; ++k) {
        float x = f[k] + xrr[k];
        p = fmaf(at[k], x >= 0.f ? x : NEG_SLOPE * x, p);
      }
#pragma unroll
      for (int m = 8; m >= 1; m >>= 1) p += __shfl_xor(p, m);
      float ex = __expf(p);
      den += ex;
#pragma unroll
      for (int k = 0; k < 8; ++k) acc8[k] = fmaf(ex, f[k], acc8[k]);
    }
    float inv = 1.f / (den + 1e-16f);
#pragma unroll
    for (int k = 0; k < 8; ++k) acc8[k] *= inv;
  }

  bf16_t* out = acc + (size_t)d * 512 + lane * 8;
  if (accumulate) {
    float old[8];
    unpack8(*(const uint4*)out, old);
#pragma unroll
    for (int k = 0; k < 8; ++k) acc8[k] += old[k];
  }
  if (bc) {
    float bcv[8];
    *(float4*)(bcv)     = *(const float4*)(bc + lane * 8);
    *(float4*)(bcv + 4) = *(const float4*)(bc + lane * 8 + 4);
#pragma unroll
    for (int k = 0; k < 8; ++k)
      acc8[k] = fmaxf(fmaf(acc8[k], inv_div, bcv[k]), 0.f);
  }
  uint4 s;
  s.x = pack2(acc8[0], acc8[1]); s.y = pack2(acc8[2], acc8[3]);
  s.z = pack2(acc8[4], acc8[5]); s.w = pack2(acc8[6], acc8[7]);
  *(uint4*)out = s;
}

// afh = relu(answer_features @ W1 + b1) -> bf16, K=6, M=64
__global__ __launch_bounds__(256) void af_hidden(
    const float* __restrict__ af, const float* __restrict__ W1,
    const float* __restrict__ b1, bf16_t* __restrict__ out, int n)
{
  int t = blockIdx.x * blockDim.x + threadIdx.x;
  if (t >= n * 64) return;
  int i = t >> 6, j = t & 63;
  const float* a = af + (size_t)i * 6;
  float s = b1[j];
#pragma unroll
  for (int k = 0; k < 6; ++k) s = fmaf(a[k], W1[k * 64 + j], s);
  out[t] = (bf16_t)f2bf(fmaxf(s, 0.f));
}

__global__ __launch_bounds__(256) void build_sim(
    const int* __restrict__ ei, int* __restrict__ ss, int* __restrict__ sd)
{
  int t = blockIdx.x * blockDim.x + threadIdx.x;
  if (t >= E_SIM + NQ) return;
  if (t < E_SIM) { ss[t] = ei[t]; sd[t] = ei[E_SIM + t]; }
  else           { ss[t] = t - E_SIM; sd[t] = t - E_SIM; }
}

// Head: per edge e: q = LN(qn[gsrc[e]]); r = LN(rn[gdst[e]] + afr[e] + cvec).
__global__ __launch_bounds__(256) void head_final(
    const float* __restrict__ qn, const float* __restrict__ rn,
    const float* __restrict__ afr, const float* __restrict__ cvec,
    const int* __restrict__ gsrc, const int* __restrict__ gdst,
    const float* __restrict__ qg, const float* __restrict__ qb,
    const float* __restrict__ rg, const float* __restrict__ rb,
    const float* __restrict__ score_bias, float* __restrict__ out, int E)
{
  int e = blockIdx.x * 4 + (threadIdx.x >> 6);
  if (e >= E) return;
  int lane = threadIdx.x & 63;

  float4 q = *(const float4*)(qn + (size_t)gsrc[e] * 256 + lane * 4);
  float s = q.x + q.y + q.z + q.w;
#pragma unroll
  for (int m = 32; m >= 1; m >>= 1) s += __shfl_xor(s, m);
  float mu = s * (1.f / 256.f);
  float dq0 = q.x - mu, dq1 = q.y - mu, dq2 = q.z - mu, dq3 = q.w - mu;
  float v = dq0 * dq0 + dq1 * dq1 + dq2 * dq2 + dq3 * dq3;
#pragma unroll
  for (int m = 32; m >= 1; m >>= 1) v += __shfl_xor(v, m);
  float rstd = rsqrtf(v * (1.f / 256.f) + 1e-5f);
  float4 g4 = *(const float4*)(qg + lane * 4);
  float4 b4 = *(const float4*)(qb + lane * 4);
  float qn0 = dq0 * rstd * g4.x + b4.x, qn1 = dq1 * rstd * g4.y + b4.y;
  float qn2 = dq2 * rstd * g4.z + b4.z, qn3 = dq3 * rstd * g4.w + b4.w;

  float4 r0 = *(const float4*)(rn + (size_t)gdst[e] * 256 + lane * 4);
  float4 r1 = *(const float4*)(afr + (size_t)e * 256 + lane * 4);
  float4 cv = *(const float4*)(cvec + lane * 4);
  float4 r;
  r.x = r0.x + r1.x + cv.x;
  r.y = r0.y + r1.y + cv.y;
  r.z = r0.z + r1.z + cv.z;
  r.w = r0.w + r1.w + cv.w;
  s = r.x + r.y + r.z + r.w;
#pragma unroll
  for (int m = 32; m >= 1; m >>= 1) s += __shfl_xor(s, m);
  mu = s * (1.f / 256.f);
  float dr0 = r.x - mu, dr1 = r.y - mu, dr2 = r.z - mu, dr3 = r.w - mu;
  v = dr0 * dr0 + dr1 * dr1 + dr2 * dr2 + dr3 * dr3;
#pragma unroll
  for (int m = 32; m >= 1; m >>= 1) v += __shfl_xor(v, m);
  rstd = rsqrtf(v * (1.f / 256.f) + 1e-5f);
  g4 = *(const float4*)(rg + lane * 4);
  b4 = *(const float4*)(rb + lane * 4);
  float rn0 = dr0 * rstd * g4.x + b4.x, rn1 = dr1 * rstd * g4.y + b4.y;
  float rn2 = dr2 * rstd * g4.z + b4.z, rn3 = dr3 * rstd * g4.w + b4.w;

  float d = qn0 * rn0 + qn1 * rn1 + qn2 * rn2 + qn3 * rn3;
#pragma unroll
  for (int m = 32; m >= 1; m >>= 1) d += __shfl_xor(d, m);
  if (lane == 0) out[e] = d * 0.0625f + score_bias[0];
}

// ---------------------------------------------------------------------------
extern "C" void kernel_launch(void* const* d_in, const int* in_sizes, int n_in,
                              void* d_out, int out_size, void* d_ws, size_t ws_size,
                              hipStream_t stream) {
  (void)in_sizes; (void)n_in; (void)out_size;
  const float* xq      = (const float*)d_in[0];
  const float* xt      = (const float*)d_in[1];
  const float* xa      = (const float*)d_in[2];
  const float* af      = (const float*)d_in[3];
  const float* qp_W    = (const float*)d_in[4];
  const float* qp_b    = (const float*)d_in[5];
  const float* tp_W    = (const float*)d_in[6];
  const float* tp_b    = (const float*)d_in[7];
  const float* ap_W    = (const float*)d_in[8];
  const float* ap_b    = (const float*)d_in[9];
  const float* afp_W1  = (const float*)d_in[10];
  const float* afp_b1  = (const float*)d_in[11];
  const float* afp_W2  = (const float*)d_in[12];
  const float* afp_b2  = (const float*)d_in[13];
  const float* conv_Wl = (const float*)d_in[14];
  const float* conv_bl = (const float*)d_in[15];
  const float* conv_Wr = (const float*)d_in[16];
  const float* conv_br = (const float*)d_in[17];
  const float* conv_att  = (const float*)d_in[18];
  const float* conv_bias = (const float*)d_in[19];
  const float* qh_W    = (const float*)d_in[20];
  const float* qh_b    = (const float*)d_in[21];
  const float* qh_g    = (const float*)d_in[22];
  const float* qh_beta = (const float*)d_in[23];
  const float* rh_W    = (const float*)d_in[24];
  const float* rh_b    = (const float*)d_in[25];
  const float* rh_g    = (const float*)d_in[26];
  const float* rh_beta = (const float*)d_in[27];
  const float* score_b = (const float*)d_in[28];
  const int* ei_gr   = (const int*)d_in[29];
  const int* ei_lt   = (const int*)d_in[30];
  const int* ei_sim  = (const int*)d_in[31];
  const int* ei_comp = (const int*)d_in[32];
  const int* ei_gen  = (const int*)d_in[33];

  char* base = (char*)d_ws;
  size_t off = 0;
  auto alloc = [&](size_t bytes) {
    void* p = base + off;
    off = (off + bytes + 255) & ~(size_t)255;
    return p;
  };
  bf16_t* hq   = (bf16_t*)alloc((size_t)NQ * 512 * 2);
  bf16_t* ht   = (bf16_t*)alloc((size_t)NT * 512 * 2);
  bf16_t* ha   = (bf16_t*)alloc((size_t)NA * 512 * 2);
  bf16_t* acct = (bf16_t*)alloc((size_t)NT * 512 * 2);   // ht ping-pong; rn f32
  bf16_t* accq = (bf16_t*)alloc((size_t)NQ * 512 * 2);   // xq-cast; hq ping-pong; qn f32
  // 100000-row arena (former xlb+xrb): conv slices at row offsets; head afh/afr
  bf16_t* arena = (bf16_t*)alloc((size_t)100000 * 512 * 2);
  bf16_t* xlb  = arena;                       // rows 0..50000 view
  bf16_t* xrb  = arena + (size_t)50000 * 512; // rows 50000..100000 view
  int* simsrc  = (int*)alloc((size_t)(E_SIM + NQ) * 4);
  int* simdst  = (int*)alloc((size_t)(E_SIM + NQ) * 4);

  // bf16-transposed weights
  bf16_t* wqp  = (bf16_t*)alloc((size_t)512 * 384 * 2);
  bf16_t* wtp  = (bf16_t*)alloc((size_t)512 * 384 * 2);
  bf16_t* wap  = (bf16_t*)alloc((size_t)512 * 384 * 2);
  bf16_t* wl   = (bf16_t*)alloc((size_t)12 * 512 * 512 * 2);
  bf16_t* wr   = (bf16_t*)alloc((size_t)12 * 512 * 512 * 2);
  bf16_t* wqh  = (bf16_t*)alloc((size_t)256 * 512 * 2);
  bf16_t* wrh0 = (bf16_t*)alloc((size_t)256 * 512 * 2);  // wrh0..2 contiguous
  bf16_t* wrh1 = (bf16_t*)alloc((size_t)256 * 512 * 2);
  bf16_t* wrh2 = (bf16_t*)alloc((size_t)256 * 512 * 2);
  float* bcAll = (float*)alloc(6 * 512 * 4);
  bf16_t* a2b    = (bf16_t*)alloc((size_t)64 * 512 * 2);
  float*  wfoldF = (float*)alloc((size_t)64 * 256 * 4);
  bf16_t* wfoldT = (bf16_t*)alloc((size_t)256 * 64 * 2);
  float*  cvec   = (float*)alloc(256 * 4);

  // Fused CSR + compaction arrays (degAll, sdegAll adjacent -> one memset)
  int* degAll   = (int*)alloc((size_t)NDTOT * 4);
  int* sdegAll  = (int*)alloc((size_t)NSTOT * 4);
  int* startAll = (int*)alloc((size_t)NDTOT * 4);
  int* cposAll  = (int*)alloc((size_t)NDTOT * 4);
  int* cidxAll  = (int*)alloc((size_t)NDTOT * 4);
  int* sposAll  = (int*)alloc((size_t)NSTOT * 4);
  int* sidxAll  = (int*)alloc((size_t)NSTOT * 4);
  int* eidxAll  = (int*)alloc((size_t)ETOT * 4);
  int* srcCAll  = (int*)alloc((size_t)ETOT * 4);
  int* posb     = (int*)alloc((size_t)ETOT * 4);
  int* bsumAll  = (int*)alloc(3 * 6 * 64 * 4);
  int* ccount   = (int*)alloc(6 * 4);
  int* scount   = (int*)alloc(6 * 4);
  if (off > ws_size) {
    fprintf(stderr, "kernel_launch: ws too small, need %zu have %zu\n", off, ws_size);
    return;
  }

  const int degOff[6] = {0, 50000, 60000, 110000, 120000, 170000};
  const int sOff[6]   = {0, 10000, 60000, 110000, 120000, 170000};
  const int eOff[6]   = {0, 50000, 100000, 150000, 240000, 340000};
  auto ROWS = [&](int r) { return arena + (size_t)r * 512; };

  auto mkDesc = [](const bf16_t* A, const bf16_t* Bt, const float* bias, void* C,
                   const int* ridx, int N, const int* Nc, int K) {
    GemmDesc d; d.A = A; d.Bt = Bt; d.bias = bias; d.C = C;
    d.ridx = ridx; d.N = N; d.Nc = Nc; d.K = K; return d;
  };
  GemmDesc dz = mkDesc(nullptr, nullptr, nullptr, nullptr, nullptr, 0, nullptr, 32);

  // wide kernel (M=512): conv + input-proj hot path
  auto launch_w = [&](GemmDesc a, GemmDesc b, GemmDesc c, GemmDesc d, int nz,
                      int maxN) {
    dim3 g(1, (maxN + 127) / 128, nz);
    bgemmW<<<g, 512, 0, stream>>>(a, b, c, d);
  };
  // legacy kernel (f32 out / M=256 / K=64 / accumulate)
  auto launch_f = [&](GemmDesc a, GemmDesc b, GemmDesc c, GemmDesc d, int nz,
                      int maxN, int M, int acc_) {
    dim3 g(M / 256, (maxN + 127) / 128, nz);
    bgemm<float><<<g, 512, 0, stream>>>(a, b, c, d, M, acc_);
  };

  // --- weight conversion + af-fold (prologue) ---
  convert_wT24<<<dim3(16, 16, 24), 256, 0, stream>>>(conv_Wl, wl, conv_Wr, wr);
  convert_wT3<<<dim3(16, 12, 3), 256, 0, stream>>>(qp_W, tp_W, ap_W, wqp, wtp, wap);
  convert_wT4h<<<dim3(8, 16, 4), 256, 0, stream>>>(qh_W, rh_W, wqh, wrh0);
  combine_bias6<<<(6 * 512 + 255) / 256, 256, 0, stream>>>(conv_bias, bcAll);
  cast_flat<<<(64 * 512 / 4 + 255) / 256, 256, 0, stream>>>(afp_W2, a2b, 64 * 512 / 4);
  launch_f(mkDesc(a2b, wrh2, nullptr, wfoldF, nullptr, 64, nullptr, 512),
           dz, dz, dz, 1, 64, 256, 0);                      // Wfold = W2 @ rh2
  convert_wT<<<dim3(8, 2, 1), 256, 0, stream>>>(wfoldF, wfoldT, 64, 256);
  fold_cvec<<<1, 256, 0, stream>>>(afp_b2, rh_W + 1024 * 256, cvec);

  // --- fused CSR build + both-side compaction ---
  build_sim<<<(E_SIM + NQ + 255) / 256, 256, 0, stream>>>(ei_sim, simsrc, simdst);
  const int* dsts[6]  = {ei_gr + E_GR, ei_gr, ei_lt, simdst,
                         ei_comp + E_COMP, ei_lt + E_LT};
  const int* srcsA[6] = {ei_gr, ei_gr + E_GR, ei_lt + E_LT, simsrc,
                         ei_comp, ei_lt};
  hipMemsetAsync(degAll, 0, (size_t)(sdegAll + NSTOT) - (size_t)degAll, stream);
  hist6<<<(ETOT + 255) / 256, 256, 0, stream>>>(
      dsts[0], dsts[1], dsts[2], dsts[3], dsts[4], dsts[5],
      srcsA[0], srcsA[1], srcsA[2], srcsA[3], srcsA[4], srcsA[5],
      degAll, sdegAll, posb);
  scan1All<<<648, 256, 0, stream>>>(degAll, sdegAll, startAll, cposAll,
                                    sposAll, bsumAll);
  scan2All<<<18, 64, 0, stream>>>(bsumAll, ccount, scount);
  scan3All<<<(3 * NDTOT + 255) / 256, 256, 0, stream>>>(startAll, cposAll,
                                                        sposAll, bsumAll);
  scatter6<<<(ETOT + 255) / 256, 256, 0, stream>>>(
      dsts[0], dsts[1], dsts[2], dsts[3], dsts[4], dsts[5],
      srcsA[0], srcsA[1], srcsA[2], srcsA[3], srcsA[4], srcsA[5],
      startAll, posb, sposAll, eidxAll, srcCAll);
  compactBoth<<<(NDTOT + NSTOT + 255) / 256, 256, 0, stream>>>(
      degAll, cposAll, cidxAll, sdegAll, sposAll, sidxAll);

  // Input projections: ONE cast + ONE z=3 wide-GEMM dispatch (K=384).
  cast3<<<((long)(N4_XQ + N4_XT + N4_XA) + 255) / 256, 256, 0, stream>>>(
      xq, xt, xa, accq, xlb, xrb);
  launch_w(mkDesc(accq, wqp, qp_b, hq, nullptr, NQ, nullptr, 384),
           mkDesc(xlb, wtp, tp_b, ht, nullptr, NT, nullptr, 384),
           mkDesc(xrb, wap, ap_b, ha, nullptr, NA, nullptr, 384),
           dz, 3, NT);

  // Layer loop: 4 wide-GEMM dispatches/layer via relation merging.
  // Arena caps (hard bounds: xr<=min(Nd,E/2), xl<=min(Ns,E)):
  //  A {gr,rgr}: gr-xl@0(10k) gr-xr@10k(25k) rgr-xl@35k(50k) rgr-xr@85k(10k)
  //  B {rlt,sim}: rlt-xl@0(50k) rlt-xr@50k(25k) sim-xl@75k(10k) sim-xr@85k(10k)
  //  C {comp}: xl@0(50k) xr@50k(50k);  D {lt}: xl@0(50k) xr@50k(25k)
  bf16_t *hq_i = hq, *ht_i = ht, *hq_o = accq, *ht_o = acct;
  for (int l = 0; l < 2; ++l) {
    const float* bc_t = bcAll + (size_t)(l * 3 + 0) * 512;
    const float* bc_q = bcAll + (size_t)(l * 3 + 1) * 512;
    const float* bc_a = bcAll + (size_t)(l * 3 + 2) * 512;
    size_t p0 = (size_t)l * 6 + 0;   // gr
    size_t p1 = (size_t)l * 6 + 1;   // rgr
    size_t p3 = (size_t)l * 6 + 3;   // rlt
    size_t p4 = (size_t)l * 6 + 4;   // sim
    size_t p5 = (size_t)l * 6 + 5;   // comp
    size_t p2 = (size_t)l * 6 + 2;   // lt

    auto gat = [&](int r, const bf16_t* xl_, const bf16_t* xr_, size_t po,
                   bf16_t* acc_, int Nd_, int accum, const float* bc, float inv) {
      gat_fused<<<(Nd_ + 3) / 4, 256, 0, stream>>>(
          xl_, xr_, srcCAll + eOff[r], startAll + degOff[r], degAll + degOff[r],
          eidxAll + eOff[r], cposAll + degOff[r], conv_att + po * 512,
          acc_, Nd_, accum, bc, inv);
    };

    // Group A: gr + rgr (z=4)
    launch_w(mkDesc(hq_i, wl + p0 * 262144, conv_bl + p0 * 512, ROWS(0),
                    sidxAll + sOff[0], 10000, scount + 0, 512),
             mkDesc(ht_i, wr + p0 * 262144, conv_br + p0 * 512, ROWS(10000),
                    cidxAll + degOff[0], 25000, ccount + 0, 512),
             mkDesc(ht_i, wl + p1 * 262144, conv_bl + p1 * 512, ROWS(35000),
                    sidxAll + sOff[1], 50000, scount + 1, 512),
             mkDesc(hq_i, wr + p1 * 262144, conv_br + p1 * 512, ROWS(85000),
                    cidxAll + degOff[1], 10000, ccount + 1, 512),
             4, 50000);
    gat(0, ROWS(0), ROWS(10000), p0, ht_o, NT, 0, nullptr, 0.f);      // gr
    gat(1, ROWS(35000), ROWS(85000), p1, hq_o, NQ, 0, nullptr, 0.f);  // rgr

    // Group B: rlt + sim (z=4)
    launch_w(mkDesc(ha, wl + p3 * 262144, conv_bl + p3 * 512, ROWS(0),
                    sidxAll + sOff[2], 50000, scount + 2, 512),
             mkDesc(ht_i, wr + p3 * 262144, conv_br + p3 * 512, ROWS(50000),
                    cidxAll + degOff[2], 25000, ccount + 2, 512),
             mkDesc(hq_i, wl + p4 * 262144, conv_bl + p4 * 512, ROWS(75000),
                    sidxAll + sOff[3], 10000, scount + 3, 512),
             mkDesc(hq_i, wr + p4 * 262144, conv_br + p4 * 512, ROWS(85000),
                    cidxAll + degOff[3], 10000, ccount + 3, 512),
             4, 50000);
    gat(2, ROWS(0), ROWS(50000), p3, ht_o, NT, 1, nullptr, 0.f);      // rlt
    gat(3, ROWS(75000), ROWS(85000), p4, hq_o, NQ, 1, bc_q, 0.5f);    // sim

    // Group C: comp (z=2)
    launch_w(mkDesc(ht_i, wl + p5 * 262144, conv_bl + p5 * 512, ROWS(0),
                    sidxAll + sOff[4], 50000, scount + 4, 512),
             mkDesc(ht_i, wr + p5 * 262144, conv_br + p5 * 512, ROWS(50000),
                    cidxAll + degOff[4], 50000, ccount + 4, 512),
             dz, dz, 2, 50000);
    gat(4, ROWS(0), ROWS(50000), p5, ht_o, NT, 1, bc_t, 1.f / 3.f);   // comp

    // Group D: lt (z=2)
    launch_w(mkDesc(ht_i, wl + p2 * 262144, conv_bl + p2 * 512, ROWS(0),
                    sidxAll + sOff[5], 50000, scount + 5, 512),
             mkDesc(ha, wr + p2 * 262144, conv_br + p2 * 512, ROWS(50000),
                    cidxAll + degOff[5], 25000, ccount + 5, 512),
             dz, dz, 2, 50000);
    gat(5, ROWS(0), ROWS(50000), p2, ha, NA, 0, bc_a, 1.f);           // lt

    bf16_t* t;
    t = hq_i; hq_i = hq_o; hq_o = t;
    t = ht_i; ht_i = ht_o; ht_o = t;
  }
  // after 2 swaps: hq_i==hq, ht_i==ht; acct/accq free.

  // Head (node-space + folded af path), z=3 dispatch {qn, rn, afr}:
  float* qn  = (float*)accq;
  float* rn  = (float*)acct;
  float* afr = (float*)xrb;
  bf16_t* afh = xlb;
  const int* gsrc = ei_gen;
  const int* gdst = ei_gen + E_GEN;

  af_hidden<<<(E_GEN * 64 + 255) / 256, 256, 0, stream>>>(af, afp_W1, afp_b1,
                                                          afh, E_GEN);
  launch_f(mkDesc(hq_i, wqh, qh_b, qn, nullptr, NQ, nullptr, 512),
           mkDesc(ht_i, wrh0, rh_b, rn, nullptr, NT, nullptr, 512),
           mkDesc(afh, wfoldT, nullptr, afr, nullptr, E_GEN, nullptr, 64),
           dz, 3, NT, 256, 0);
  launch_f(mkDesc(ha, wrh1, nullptr, rn, nullptr, NA, nullptr, 512),
           dz, dz, dz, 1, NA, 256, 1);                      // rn += ha @ rh1
  head_final<<<(E_GEN + 3) / 4, 256, 0, stream>>>(
      qn, rn, afr, cvec, gsrc, gdst,
      qh_g, qh_beta, rh_g, rh_beta, score_b, (float*)d_out, E_GEN);
}

// Round 26
// 1141.952 us; speedup vs baseline: 1.0864x; 1.0864x over previous
//
#include <hip/hip_runtime.h>
#include <cstdio>
#include <type_traits>

#define NQ 10000
#define NT 50000
#define NA 50000
#define E_GR 50000
#define E_LT 50000
#define E_SIM 80000
#define E_COMP 100000
#define E_GEN 50000
#define NEG_SLOPE 0.2f

// Concatenated CSR tables (compile-time). Rel order: gr, rgr, rlt, sim, comp, lt
#define NDTOT 220000
#define NSTOT 220000
#define ETOT  390000
__device__ __constant__ const int c_degOff[7]  = {0, 50000, 60000, 110000, 120000, 170000, 220000};
__device__ __constant__ const int c_sOff[7]    = {0, 10000, 60000, 110000, 120000, 170000, 220000};
__device__ __constant__ const int c_eOff[7]    = {0, 50000, 100000, 150000, 240000, 340000, 390000};
__device__ __constant__ const int c_nb[6]      = {49, 10, 49, 10, 49, 49};
__device__ __constant__ const int c_nbOff[7]   = {0, 49, 59, 108, 118, 167, 216};
__device__ __constant__ const int c_snb[6]     = {10, 49, 49, 10, 49, 49};
__device__ __constant__ const int c_snbOff[7]  = {0, 10, 59, 108, 118, 167, 216};

typedef unsigned short bf16_t;
typedef unsigned int u32;
typedef __attribute__((ext_vector_type(8))) short short8v;
typedef __attribute__((ext_vector_type(4))) float f32x4;

__device__ __forceinline__ float bf2f(u32 bits) { return __uint_as_float(bits << 16); }
__device__ __forceinline__ u32 f2bf(float f) {
  u32 u = __float_as_uint(f);
  return (u + 0x7FFFu + ((u >> 16) & 1u)) >> 16;   // RTNE
}
__device__ __forceinline__ u32 pack2(float a, float b) { return f2bf(a) | (f2bf(b) << 16); }
__device__ __forceinline__ void unpack8(uint4 u, float* f) {
  f[0] = bf2f(u.x & 0xffffu); f[1] = bf2f(u.x >> 16);
  f[2] = bf2f(u.y & 0xffffu); f[3] = bf2f(u.y >> 16);
  f[4] = bf2f(u.z & 0xffffu); f[5] = bf2f(u.z >> 16);
  f[6] = bf2f(u.w & 0xffffu); f[7] = bf2f(u.w >> 16);
}

// async global->LDS, 16B per lane; LDS dest = wave-uniform base + lane*16.
__device__ __forceinline__ void gload16(const void* g, void* l) {
  __builtin_amdgcn_global_load_lds(
      (const __attribute__((address_space(1))) void*)g,
      (__attribute__((address_space(3))) void*)l, 16, 0, 0);
}

// GEMM descriptor (per z-slice): C = A @ Bt^T (+bias | +=C), rows N (or *Nc),
// optional row-gather ridx, per-slice K. Optional K-concat: for k>=512 the
// loop switches to (A2, B2) — computes A@Bt^T + A2@B2t^T in one pass
// (row stride lda for all four operands; lda==K when no concat).
struct GemmDesc {
  const bf16_t* A; const bf16_t* A2; const bf16_t* Bt; const bf16_t* B2;
  const float* bias; void* C;
  const int* ridx; int N; const int* Nc; int K; int lda;
};

// ---------------------------------------------------------------------------
// MFMA bf16 GEMM, up to 4 z-slices (r12 banked structure, ~570 TF/GEMM).
// 128x256 tile, BK=32, 8 waves (2x4), acc[4][4]; 3x24KB LDS (2 blocks/CU),
// rotation s%3, ONE barrier/step. Both-sides octet XOR (rule #21).
// XCD-grouped band swizzle; slice N==0 -> uniform exit before any barrier.
// ---------------------------------------------------------------------------
template <typename CT>
__global__ __launch_bounds__(512, 4) void bgemm(
    GemmDesc d0, GemmDesc d1, GemmDesc d2, GemmDesc d3, int M, int accumulate)
{
  __shared__ short lds[3][12288];   // [buf][A: 0..4095 | B: 4096..12287]
  const int z = blockIdx.z;
  GemmDesc d = (z == 3) ? d3 : (z == 2) ? d2 : (z == 1) ? d1 : d0;
  int N = d.Nc ? *d.Nc : d.N;
  const int K = d.K;

  const int tid = threadIdx.x;
  const int ncol = gridDim.x;
  const int nband = (N + 127) >> 7;
  int lin = blockIdx.y * ncol + blockIdx.x;
  if (lin >= ncol * nband) return;          // uniform exit, before barriers

  int band, col;
  const int full = (nband >> 3) * 8 * ncol;
  if (lin < full) {
    int g = lin >> 3, x = lin & 7;
    band = x + 8 * (g / ncol);
    col  = g % ncol;
  } else {
    int r = lin - full;
    band = (nband & ~7) + r / ncol;
    col  = r % ncol;
  }
  const int bm = band * 128, bn = col * 256;

  const int lane = tid & 63;
  const int w = tid >> 6;
  const int wr = w >> 2, wc = w & 3;
  const int fr = lane & 15, fg = lane >> 4;

  const int kg = (((tid & 3) ^ ((tid >> 3) & 3)) << 3);
  const int rr = tid >> 2;
  int ra = min(bm + rr, N - 1);
  const size_t arow = (size_t)(d.ridx ? d.ridx[ra] : ra) * d.lda;
  const bf16_t* gA0 = d.A + arow + kg;
  const bf16_t* gA1 = (d.A2 ? d.A2 : d.A) + arow + kg;
  const bf16_t* gB0 = d.Bt + (size_t)(bn + rr) * d.lda + kg;
  const bf16_t* gB1 = d.Bt + (size_t)(bn + 128 + rr) * d.lda + kg;
  const bf16_t* gB0b = (d.B2 ? d.B2 : d.Bt) + (size_t)(bn + rr) * d.lda + kg;
  const bf16_t* gB1b = (d.B2 ? d.B2 : d.Bt) + (size_t)(bn + 128 + rr) * d.lda + kg;
  const bool cat = (d.A2 != nullptr);
  const int wb = w << 9;

  f32x4 acc[4][4];
#pragma unroll
  for (int i = 0; i < 4; ++i)
#pragma unroll
    for (int j = 0; j < 4; ++j) acc[i][j] = (f32x4){0.f, 0.f, 0.f, 0.f};

  auto stage = [&](int buf, int k0) {
    short* base = &lds[buf][0];
    const bool hi = cat && (k0 >= 512);
    const int ko = hi ? k0 - 512 : k0;
    gload16((hi ? gA1 : gA0) + ko, base + wb);
    gload16((hi ? gB0b : gB0) + ko, base + 4096 + wb);
    gload16((hi ? gB1b : gB1) + ko, base + 8192 + wb);
  };

  const int nsteps = K >> 5;
  stage(0, 0);
  const int co = (fg ^ ((fr >> 1) & 3)) << 3;
  for (int s = 0; s < nsteps; ++s) {
    const int cur = s % 3;
    if (s + 1 < nsteps) {
      stage((s + 1) % 3, (s + 1) << 5);
      asm volatile("s_waitcnt vmcnt(3)" ::: "memory");
    } else {
      asm volatile("s_waitcnt vmcnt(0)" ::: "memory");
    }
    __builtin_amdgcn_s_barrier();
    asm volatile("" ::: "memory");
    const short* LA = &lds[cur][0];
    const short* LB = &lds[cur][4096];
    short8v b[4];
#pragma unroll
    for (int j = 0; j < 4; ++j) {
      int R = wc * 64 + j * 16 + fr;
      b[j] = *(const short8v*)&LB[R * 32 + co];
    }
#pragma unroll
    for (int i = 0; i < 4; ++i) {
      int R = wr * 64 + i * 16 + fr;
      short8v a = *(const short8v*)&LA[R * 32 + co];
#pragma unroll
      for (int j = 0; j < 4; ++j)
        acc[i][j] = __builtin_amdgcn_mfma_f32_16x16x32_bf16(b[j], a,
                                                            acc[i][j], 0, 0, 0);
    }
    asm volatile("" ::: "memory");
  }

  CT* C = (CT*)d.C;
  float4 bv[4];
#pragma unroll
  for (int j = 0; j < 4; ++j) {
    bv[j] = make_float4(0.f, 0.f, 0.f, 0.f);
    if (!accumulate && d.bias)
      bv[j] = *(const float4*)(d.bias + bn + wc * 64 + j * 16 + fg * 4);
  }
#pragma unroll
  for (int i = 0; i < 4; ++i) {
    const int n = bm + wr * 64 + i * 16 + fr;
    if (n >= N) continue;
#pragma unroll
    for (int j = 0; j < 4; ++j) {
      const int m0 = bn + wc * 64 + j * 16 + fg * 4;
      f32x4 v = acc[i][j];
      if constexpr (std::is_same<CT, float>::value) {
        float* p = C + (size_t)n * M + m0;
        if (accumulate) {
          float4 o = *(float4*)p;
          o.x += v[0]; o.y += v[1]; o.z += v[2]; o.w += v[3];
          *(float4*)p = o;
        } else {
          *(float4*)p = make_float4(v[0] + bv[j].x, v[1] + bv[j].y,
                                    v[2] + bv[j].z, v[3] + bv[j].w);
        }
      } else {
        uint2 o;
        o.x = pack2(v[0] + bv[j].x, v[1] + bv[j].y);
        o.y = pack2(v[2] + bv[j].z, v[3] + bv[j].w);
        *(uint2*)(C + (size_t)n * M + m0) = o;
      }
    }
  }
}

// core transpose tile: fp32 W[K][M] slice -> bf16 Wt[M][K] slice
__device__ __forceinline__ void wT_tile(
    const float* __restrict__ W, bf16_t* __restrict__ Wt, int K, int M)
{
  __shared__ float sm[32][33];
  int mb = blockIdx.x * 32, kb = blockIdx.y * 32;
  int tx = threadIdx.x & 31, ty = threadIdx.x >> 5;
#pragma unroll
  for (int i = 0; i < 4; ++i)
    sm[ty + i * 8][tx] = W[(size_t)(kb + ty + i * 8) * M + mb + tx];
  __syncthreads();
#pragma unroll
  for (int i = 0; i < 4; ++i)
    Wt[(size_t)(mb + ty + i * 8) * K + kb + tx] = (bf16_t)f2bf(sm[tx][ty + i * 8]);
}

__global__ __launch_bounds__(256) void convert_wT(
    const float* __restrict__ W, bf16_t* __restrict__ Wt, int K, int M)
{
  wT_tile(W + (size_t)blockIdx.z * K * M, Wt + (size_t)blockIdx.z * K * M, K, M);
}
__global__ __launch_bounds__(256) void convert_wT24(
    const float* __restrict__ Wl, bf16_t* __restrict__ wl,
    const float* __restrict__ Wr, bf16_t* __restrict__ wr)
{
  int z = blockIdx.z;
  size_t o = (size_t)(z < 12 ? z : z - 12) * 512 * 512;
  if (z < 12) wT_tile(Wl + o, wl + o, 512, 512);
  else        wT_tile(Wr + o, wr + o, 512, 512);
}
__global__ __launch_bounds__(256) void convert_wT3(
    const float* __restrict__ W0, const float* __restrict__ W1,
    const float* __restrict__ W2, bf16_t* __restrict__ T0,
    bf16_t* __restrict__ T1, bf16_t* __restrict__ T2)
{
  int z = blockIdx.z;
  const float* W = z == 0 ? W0 : z == 1 ? W1 : W2;
  bf16_t* T = z == 0 ? T0 : z == 1 ? T1 : T2;
  wT_tile(W, T, 384, 512);
}
__global__ __launch_bounds__(256) void convert_wT4h(
    const float* __restrict__ qh, const float* __restrict__ rh,
    bf16_t* __restrict__ wqh, bf16_t* __restrict__ wrh)
{
  int z = blockIdx.z;
  if (z == 0) wT_tile(qh, wqh, 512, 256);
  else        wT_tile(rh + (size_t)(z - 1) * 512 * 256,
                      wrh + (size_t)(z - 1) * 256 * 512, 512, 256);
}

// flat fp32 -> bf16 cast (n4 float4s)
__global__ __launch_bounds__(256) void cast_flat(
    const float* __restrict__ in, bf16_t* __restrict__ out, int n4)
{
  int t = blockIdx.x * 256 + threadIdx.x;
  if (t >= n4) return;
  float4 v = ((const float4*)in)[t];
  uint2 o;
  o.x = pack2(v.x, v.y);
  o.y = pack2(v.z, v.w);
  ((uint2*)out)[t] = o;
}

// cvec[m] = sum_k afp_b2[k] * rh2[k][m]
__global__ __launch_bounds__(256) void fold_cvec(
    const float* __restrict__ b2, const float* __restrict__ rh2,
    float* __restrict__ cvec)
{
  int m = threadIdx.x;
  float s = 0.f;
  for (int k = 0; k < 512; ++k) s = fmaf(b2[k], rh2[(size_t)k * 256 + m], s);
  cvec[m] = s;
}

// fused input casts: xq->xqb, xt->xlb, xa->xrb (float4 granularity)
#define N4_XQ (NQ * 96)
#define N4_XT (NT * 96)
#define N4_XA (NA * 96)
__global__ __launch_bounds__(256) void cast3(
    const float* __restrict__ xq, const float* __restrict__ xt,
    const float* __restrict__ xa, bf16_t* __restrict__ xqb,
    bf16_t* __restrict__ xtb, bf16_t* __restrict__ xab)
{
  long g = (long)blockIdx.x * 256 + threadIdx.x;
  const float* in; bf16_t* out; long idx;
  if (g < N4_XQ)                { in = xq; out = xqb; idx = g; }
  else if (g < N4_XQ + N4_XT)   { in = xt; out = xtb; idx = g - N4_XQ; }
  else if (g < N4_XQ + N4_XT + N4_XA) { in = xa; out = xab; idx = g - N4_XQ - N4_XT; }
  else return;
  float4 v = ((const float4*)in)[idx];
  uint2 o;
  o.x = pack2(v.x, v.y);
  o.y = pack2(v.z, v.w);
  ((uint2*)out)[idx] = o;
}

__global__ __launch_bounds__(256) void combine_bias6(
    const float* __restrict__ cb, float* __restrict__ bcAll)
{
  int g = blockIdx.x * 256 + threadIdx.x;
  if (g >= 6 * 512) return;
  int row = g >> 9, j = g & 511;
  int l = row / 3, kind = row % 3;
  const float* b = cb + (size_t)l * 6 * 512;
  float v;
  if (kind == 0)      v = (b[0 * 512 + j] + b[3 * 512 + j] + b[5 * 512 + j]) / 3.f;
  else if (kind == 1) v = (b[1 * 512 + j] + b[4 * 512 + j]) * 0.5f;
  else                v = b[2 * 512 + j];
  bcAll[(size_t)row * 512 + j] = v;
}

// ---------------------------------------------------------------------------
// Fused CSR build + compactions (wide 3-phase scan; jobs batched per phase).
// ---------------------------------------------------------------------------
__device__ __forceinline__ int find_rel6(int g, const int* off) {
  int r = 0;
#pragma unroll
  for (int k = 1; k < 6; ++k) r += (g >= off[k]);
  return r;
}

__global__ __launch_bounds__(256) void hist6(
    const int* __restrict__ d0, const int* __restrict__ d1,
    const int* __restrict__ d2, const int* __restrict__ d3,
    const int* __restrict__ d4, const int* __restrict__ d5,
    const int* __restrict__ s0p, const int* __restrict__ s1p,
    const int* __restrict__ s2p, const int* __restrict__ s3p,
    const int* __restrict__ s4p, const int* __restrict__ s5p,
    int* __restrict__ degAll, int* __restrict__ sdegAll, int* __restrict__ pos)
{
  int g = blockIdx.x * 256 + threadIdx.x;
  if (g >= ETOT) return;
  int r = find_rel6(g, c_eOff);
  int le = g - c_eOff[r];
  const int* dp = r == 0 ? d0 : r == 1 ? d1 : r == 2 ? d2 : r == 3 ? d3
                : r == 4 ? d4 : d5;
  const int* sp = r == 0 ? s0p : r == 1 ? s1p : r == 2 ? s2p : r == 3 ? s3p
                : r == 4 ? s4p : s5p;
  pos[g] = atomicAdd(&degAll[c_degOff[r] + dp[le]], 1);
  atomicAdd(&sdegAll[c_sOff[r] + sp[le]], 1);
}

// phase 1: 648 blocks = job(3) x 216 relation-blocks; 1024 items each.
__global__ __launch_bounds__(256) void scan1All(
    const int* __restrict__ degAll, const int* __restrict__ sdegAll,
    int* __restrict__ startAll, int* __restrict__ cposAll,
    int* __restrict__ sposAll, int* __restrict__ bsumAll)
{
  __shared__ int sm[256];
  int j = blockIdx.x / 216, bb = blockIdx.x % 216;
  const int* nbOff = (j == 2) ? c_snbOff : c_nbOff;
  const int* dOff  = (j == 2) ? c_sOff : c_degOff;
  const int* in    = (j == 2) ? sdegAll : degAll;
  int* out = j == 0 ? startAll : j == 1 ? cposAll : sposAll;
  int r = 0;
#pragma unroll
  for (int k = 1; k < 6; ++k) r += (bb >= nbOff[k]);
  int lb = bb - nbOff[r];
  int base0 = dOff[r], n = dOff[r + 1] - base0;
  int t = threadIdx.x;
  int base = lb * 1024 + t * 4;
  int v[4], sum = 0;
#pragma unroll
  for (int k = 0; k < 4; ++k) {
    int raw = (base + k < n) ? in[base0 + base + k] : 0;
    v[k] = j == 0 ? raw : j == 1 ? (raw >= 2 ? 1 : 0) : (raw >= 1 ? 1 : 0);
    sum += v[k];
  }
  sm[t] = sum;
  __syncthreads();
  for (int off = 1; off < 256; off <<= 1) {
    int x = (t >= off) ? sm[t - off] : 0;
    __syncthreads();
    sm[t] += x;
    __syncthreads();
  }
  int run = (t > 0) ? sm[t - 1] : 0;
  if (t == 255) bsumAll[j * 384 + r * 64 + lb] = sm[255];
#pragma unroll
  for (int k = 0; k < 4; ++k) {
    if (base + k < n) out[base0 + base + k] = run;
    run += v[k];
  }
}

// phase 2: 18 blocks (job x rel), exclusive scan of block sums (<=64).
__global__ __launch_bounds__(64) void scan2All(
    int* __restrict__ bsumAll, int* __restrict__ ccount, int* __restrict__ scount)
{
  __shared__ int sm[64];
  int j = blockIdx.x / 6, r = blockIdx.x % 6;
  int nb = (j == 2) ? c_snb[r] : c_nb[r];
  int t = threadIdx.x;
  int v = (t < nb) ? bsumAll[j * 384 + r * 64 + t] : 0;
  sm[t] = v;
  __syncthreads();
  for (int off = 1; off < 64; off <<= 1) {
    int x = (t >= off) ? sm[t - off] : 0;
    __syncthreads();
    sm[t] += x;
    __syncthreads();
  }
  if (t < nb) bsumAll[j * 384 + r * 64 + t] = sm[t] - v;   // exclusive
  if (t == nb - 1) {
    if (j == 1) ccount[r] = sm[t];
    if (j == 2) scount[r] = sm[t];
  }
}

// phase 3: add block offsets; grid covers 3 x 220000.
__global__ __launch_bounds__(256) void scan3All(
    int* __restrict__ startAll, int* __restrict__ cposAll,
    int* __restrict__ sposAll, const int* __restrict__ bsumAll)
{
  int g = blockIdx.x * 256 + threadIdx.x;
  if (g >= 3 * NDTOT) return;
  int j = g / NDTOT, ln0 = g % NDTOT;
  const int* dOff = (j == 2) ? c_sOff : c_degOff;
  int* out = j == 0 ? startAll : j == 1 ? cposAll : sposAll;
  int r = find_rel6(ln0, dOff);
  int ln = ln0 - dOff[r];
  out[ln0] += bsumAll[j * 384 + r * 64 + (ln >> 10)];
}

__global__ __launch_bounds__(256) void scatter6(
    const int* __restrict__ d0, const int* __restrict__ d1,
    const int* __restrict__ d2, const int* __restrict__ d3,
    const int* __restrict__ d4, const int* __restrict__ d5,
    const int* __restrict__ s0p, const int* __restrict__ s1p,
    const int* __restrict__ s2p, const int* __restrict__ s3p,
    const int* __restrict__ s4p, const int* __restrict__ s5p,
    const int* __restrict__ startAll, const int* __restrict__ pos,
    const int* __restrict__ sposAll,
    int* __restrict__ eidxAll, int* __restrict__ srcCAll)
{
  int g = blockIdx.x * 256 + threadIdx.x;
  if (g >= ETOT) return;
  int r = find_rel6(g, c_eOff);
  int le = g - c_eOff[r];
  const int* dp = r == 0 ? d0 : r == 1 ? d1 : r == 2 ? d2 : r == 3 ? d3
                : r == 4 ? d4 : d5;
  const int* sp = r == 0 ? s0p : r == 1 ? s1p : r == 2 ? s2p : r == 3 ? s3p
                : r == 4 ? s4p : s5p;
  eidxAll[c_eOff[r] + startAll[c_degOff[r] + dp[le]] + pos[g]] = le;
  srcCAll[g] = sposAll[c_sOff[r] + sp[le]];
}

// one kernel for both compactions (dst deg>=2 then src deg>=1)
__global__ __launch_bounds__(256) void compactBoth(
    const int* __restrict__ degAll, const int* __restrict__ cposAll,
    int* __restrict__ cidxAll,
    const int* __restrict__ sdegAll, const int* __restrict__ sposAll,
    int* __restrict__ sidxAll)
{
  int g = blockIdx.x * 256 + threadIdx.x;
  if (g < NDTOT) {
    if (degAll[g] >= 2) {
      int r = find_rel6(g, c_degOff);
      cidxAll[c_degOff[r] + cposAll[g]] = g - c_degOff[r];
    }
  } else if (g < NDTOT + NSTOT) {
    int h = g - NDTOT;
    if (sdegAll[h] >= 1) {
      int r = find_rel6(h, c_sOff);
      sidxAll[c_sOff[r] + sposAll[h]] = h - c_sOff[r];
    }
  }
}

// ---------------------------------------------------------------------------
// Fused GATv2: one wave per dst node. deg==0 -> 0; deg==1 -> xl[srcC];
// deg>=2 reads compacted xr at cpos[d]. srcC pre-remapped. Edge pipelined.
// ---------------------------------------------------------------------------
__global__ __launch_bounds__(256) void gat_fused(
    const bf16_t* __restrict__ xl, const bf16_t* __restrict__ xr,
    const int* __restrict__ srcC, const int* __restrict__ start,
    const int* __restrict__ deg, const int* __restrict__ eidx,
    const int* __restrict__ cpos, const float* __restrict__ att,
    bf16_t* __restrict__ acc, int Nd, int accumulate,
    const float* __restrict__ bc, float inv_div)
{
  int d = blockIdx.x * 4 + (threadIdx.x >> 6);
  if (d >= Nd) return;
  int lane = threadIdx.x & 63;

  float acc8[8] = {0.f, 0.f, 0.f, 0.f, 0.f, 0.f, 0.f, 0.f};
  int n = deg[d], s0 = start[d];
  if (n == 1) {
    int s = srcC[eidx[s0]];
    unpack8(*(const uint4*)(xl + (size_t)s * 512 + lane * 8), acc8);
  } else if (n > 1) {
    float xrr[8];
    unpack8(*(const uint4*)(xr + (size_t)cpos[d] * 512 + lane * 8), xrr);
    float at[8];
    *(float4*)(at)     = *(const float4*)(att + lane * 8);
    *(float4*)(at + 4) = *(const float4*)(att + lane * 8 + 4);
    float den = 0.f;
    int sN = srcC[eidx[s0]];
    for (int i = 0; i < n; ++i) {
      int s = sN;
      if (i + 1 < n) sN = srcC[eidx[s0 + i + 1]];
      float f[8];
      unpack8(*(const uint4*)(xl + (size_t)s * 512 + lane * 8), f);
      float p = 0.f;
#pragma unroll
      for (int k = 0; k < 8; ++k) {
        float x = f[k] + xrr[k];
        p = fmaf(at[k], x >= 0.f ? x : NEG_SLOPE * x, p);
      }
#pragma unroll
      for (int m = 8; m >= 1; m >>= 1) p += __shfl_xor(p, m);
      float ex = __expf(p);
      den += ex;
#pragma unroll
      for (int k = 0; k < 8; ++k) acc8[k] = fmaf(ex, f[k], acc8[k]);
    }
    float inv = 1.f / (den + 1e-16f);
#pragma unroll
    for (int k = 0; k < 8; ++k) acc8[k] *= inv;
  }

  bf16_t* out = acc + (size_t)d * 512 + lane * 8;
  if (accumulate) {
    float old[8];
    unpack8(*(const uint4*)out, old);
#pragma unroll
    for (int k = 0; k < 8; ++k) acc8[k] += old[k];
  }
  if (bc) {
    float bcv[8];
    *(float4*)(bcv)     = *(const float4*)(bc + lane * 8);
    *(float4*)(bcv + 4) = *(const float4*)(bc + lane * 8 + 4);
#pragma unroll
    for (int k = 0; k < 8; ++k)
      acc8[k] = fmaxf(fmaf(acc8[k], inv_div, bcv[k]), 0.f);
  }
  uint4 s;
  s.x = pack2(acc8[0], acc8[1]); s.y = pack2(acc8[2], acc8[3]);
  s.z = pack2(acc8[4], acc8[5]); s.w = pack2(acc8[6], acc8[7]);
  *(uint4*)out = s;
}

// afh = relu(answer_features @ W1 + b1) -> bf16, K=6, M=64
__global__ __launch_bounds__(256) void af_hidden(
    const float* __restrict__ af, const float* __restrict__ W1,
    const float* __restrict__ b1, bf16_t* __restrict__ out, int n)
{
  int t = blockIdx.x * blockDim.x + threadIdx.x;
  if (t >= n * 64) return;
  int i = t >> 6, j = t & 63;
  const float* a = af + (size_t)i * 6;
  float s = b1[j];
#pragma unroll
  for (int k = 0; k < 6; ++k) s = fmaf(a[k], W1[k * 64 + j], s);
  out[t] = (bf16_t)f2bf(fmaxf(s, 0.f));
}

__global__ __launch_bounds__(256) void build_sim(
    const int* __restrict__ ei, int* __restrict__ ss, int* __restrict__ sd)
{
  int t = blockIdx.x * blockDim.x + threadIdx.x;
  if (t >= E_SIM + NQ) return;
  if (t < E_SIM) { ss[t] = ei[t]; sd[t] = ei[E_SIM + t]; }
  else           { ss[t] = t - E_SIM; sd[t] = t - E_SIM; }
}

// Head: per edge e: q = LN(qn[gsrc[e]]); r = LN(rn[gdst[e]] + afr[e] + cvec).
__global__ __launch_bounds__(256) void head_final(
    const float* __restrict__ qn, const float* __restrict__ rn,
    const float* __restrict__ afr, const float* __restrict__ cvec,
    const int* __restrict__ gsrc, const int* __restrict__ gdst,
    const float* __restrict__ qg, const float* __restrict__ qb,
    const float* __restrict__ rg, const float* __restrict__ rb,
    const float* __restrict__ score_bias, float* __restrict__ out, int E)
{
  int e = blockIdx.x * 4 + (threadIdx.x >> 6);
  if (e >= E) return;
  int lane = threadIdx.x & 63;

  float4 q = *(const float4*)(qn + (size_t)gsrc[e] * 256 + lane * 4);
  float s = q.x + q.y + q.z + q.w;
#pragma unroll
  for (int m = 32; m >= 1; m >>= 1) s += __shfl_xor(s, m);
  float mu = s * (1.f / 256.f);
  float dq0 = q.x - mu, dq1 = q.y - mu, dq2 = q.z - mu, dq3 = q.w - mu;
  float v = dq0 * dq0 + dq1 * dq1 + dq2 * dq2 + dq3 * dq3;
#pragma unroll
  for (int m = 32; m >= 1; m >>= 1) v += __shfl_xor(v, m);
  float rstd = rsqrtf(v * (1.f / 256.f) + 1e-5f);
  float4 g4 = *(const float4*)(qg + lane * 4);
  float4 b4 = *(const float4*)(qb + lane * 4);
  float qn0 = dq0 * rstd * g4.x + b4.x, qn1 = dq1 * rstd * g4.y + b4.y;
  float qn2 = dq2 * rstd * g4.z + b4.z, qn3 = dq3 * rstd * g4.w + b4.w;

  float4 r0 = *(const float4*)(rn + (size_t)gdst[e] * 256 + lane * 4);
  float4 r1 = *(const float4*)(afr + (size_t)e * 256 + lane * 4);
  float4 cv = *(const float4*)(cvec + lane * 4);
  float4 r;
  r.x = r0.x + r1.x + cv.x;
  r.y = r0.y + r1.y + cv.y;
  r.z = r0.z + r1.z + cv.z;
  r.w = r0.w + r1.w + cv.w;
  s = r.x + r.y + r.z + r.w;
#pragma unroll
  for (int m = 32; m >= 1; m >>= 1) s += __shfl_xor(s, m);
  mu = s * (1.f / 256.f);
  float dr0 = r.x - mu, dr1 = r.y - mu, dr2 = r.z - mu, dr3 = r.w - mu;
  v = dr0 * dr0 + dr1 * dr1 + dr2 * dr2 + dr3 * dr3;
#pragma unroll
  for (int m = 32; m >= 1; m >>= 1) v += __shfl_xor(v, m);
  rstd = rsqrtf(v * (1.f / 256.f) + 1e-5f);
  g4 = *(const float4*)(rg + lane * 4);
  b4 = *(const float4*)(rb + lane * 4);
  float rn0 = dr0 * rstd * g4.x + b4.x, rn1 = dr1 * rstd * g4.y + b4.y;
  float rn2 = dr2 * rstd * g4.z + b4.z, rn3 = dr3 * rstd * g4.w + b4.w;

  float d = qn0 * rn0 + qn1 * rn1 + qn2 * rn2 + qn3 * rn3;
#pragma unroll
  for (int m = 32; m >= 1; m >>= 1) d += __shfl_xor(d, m);
  if (lane == 0) out[e] = d * 0.0625f + score_bias[0];
}

// ---------------------------------------------------------------------------
extern "C" void kernel_launch(void* const* d_in, const int* in_sizes, int n_in,
                              void* d_out, int out_size, void* d_ws, size_t ws_size,
                              hipStream_t stream) {
  (void)in_sizes; (void)n_in; (void)out_size;
  const float* xq      = (const float*)d_in[0];
  const float* xt      = (const float*)d_in[1];
  const float* xa      = (const float*)d_in[2];
  const float* af      = (const float*)d_in[3];
  const float* qp_W    = (const float*)d_in[4];
  const float* qp_b    = (const float*)d_in[5];
  const float* tp_W    = (const float*)d_in[6];
  const float* tp_b    = (const float*)d_in[7];
  const float* ap_W    = (const float*)d_in[8];
  const float* ap_b    = (const float*)d_in[9];
  const float* afp_W1  = (const float*)d_in[10];
  const float* afp_b1  = (const float*)d_in[11];
  const float* afp_W2  = (const float*)d_in[12];
  const float* afp_b2  = (const float*)d_in[13];
  const float* conv_Wl = (const float*)d_in[14];
  const float* conv_bl = (const float*)d_in[15];
  const float* conv_Wr = (const float*)d_in[16];
  const float* conv_br = (const float*)d_in[17];
  const float* conv_att  = (const float*)d_in[18];
  const float* conv_bias = (const float*)d_in[19];
  const float* qh_W    = (const float*)d_in[20];
  const float* qh_b    = (const float*)d_in[21];
  const float* qh_g    = (const float*)d_in[22];
  const float* qh_beta = (const float*)d_in[23];
  const float* rh_W    = (const float*)d_in[24];
  const float* rh_b    = (const float*)d_in[25];
  const float* rh_g    = (const float*)d_in[26];
  const float* rh_beta = (const float*)d_in[27];
  const float* score_b = (const float*)d_in[28];
  const int* ei_gr   = (const int*)d_in[29];
  const int* ei_lt   = (const int*)d_in[30];
  const int* ei_sim  = (const int*)d_in[31];
  const int* ei_comp = (const int*)d_in[32];
  const int* ei_gen  = (const int*)d_in[33];

  char* base = (char*)d_ws;
  size_t off = 0;
  auto alloc = [&](size_t bytes) {
    void* p = base + off;
    off = (off + bytes + 255) & ~(size_t)255;
    return p;
  };
  bf16_t* hq   = (bf16_t*)alloc((size_t)NQ * 512 * 2);
  bf16_t* ht   = (bf16_t*)alloc((size_t)NT * 512 * 2);
  bf16_t* ha   = (bf16_t*)alloc((size_t)NA * 512 * 2);
  bf16_t* acct = (bf16_t*)alloc((size_t)NT * 512 * 2);   // ht ping-pong; rn f32
  bf16_t* accq = (bf16_t*)alloc((size_t)NQ * 512 * 2);   // xq-cast; hq ping-pong; qn f32
  // 100000-row arena (former xlb+xrb): conv slices at row offsets; head afh/afr
  bf16_t* arena = (bf16_t*)alloc((size_t)100000 * 512 * 2);
  bf16_t* xlb  = arena;                       // rows 0..50000 view
  bf16_t* xrb  = arena + (size_t)50000 * 512; // rows 50000..100000 view
  int* simsrc  = (int*)alloc((size_t)(E_SIM + NQ) * 4);
  int* simdst  = (int*)alloc((size_t)(E_SIM + NQ) * 4);

  // bf16-transposed weights
  bf16_t* wqp  = (bf16_t*)alloc((size_t)512 * 384 * 2);
  bf16_t* wtp  = (bf16_t*)alloc((size_t)512 * 384 * 2);
  bf16_t* wap  = (bf16_t*)alloc((size_t)512 * 384 * 2);
  bf16_t* wl   = (bf16_t*)alloc((size_t)12 * 512 * 512 * 2);
  bf16_t* wr   = (bf16_t*)alloc((size_t)12 * 512 * 512 * 2);
  bf16_t* wqh  = (bf16_t*)alloc((size_t)256 * 512 * 2);
  bf16_t* wrh0 = (bf16_t*)alloc((size_t)256 * 512 * 2);  // wrh0..2 contiguous
  bf16_t* wrh1 = (bf16_t*)alloc((size_t)256 * 512 * 2);
  bf16_t* wrh2 = (bf16_t*)alloc((size_t)256 * 512 * 2);
  float* bcAll = (float*)alloc(6 * 512 * 4);
  bf16_t* a2b    = (bf16_t*)alloc((size_t)64 * 512 * 2);
  float*  wfoldF = (float*)alloc((size_t)64 * 256 * 4);
  bf16_t* wfoldT = (bf16_t*)alloc((size_t)256 * 64 * 2);
  float*  cvec   = (float*)alloc(256 * 4);

  // Fused CSR + compaction arrays (degAll, sdegAll adjacent -> one memset)
  int* degAll   = (int*)alloc((size_t)NDTOT * 4);
  int* sdegAll  = (int*)alloc((size_t)NSTOT * 4);
  int* startAll = (int*)alloc((size_t)NDTOT * 4);
  int* cposAll  = (int*)alloc((size_t)NDTOT * 4);
  int* cidxAll  = (int*)alloc((size_t)NDTOT * 4);
  int* sposAll  = (int*)alloc((size_t)NSTOT * 4);
  int* sidxAll  = (int*)alloc((size_t)NSTOT * 4);
  int* eidxAll  = (int*)alloc((size_t)ETOT * 4);
  int* srcCAll  = (int*)alloc((size_t)ETOT * 4);
  int* posb     = (int*)alloc((size_t)ETOT * 4);
  int* bsumAll  = (int*)alloc(3 * 6 * 64 * 4);
  int* ccount   = (int*)alloc(6 * 4);
  int* scount   = (int*)alloc(6 * 4);
  if (off > ws_size) {
    fprintf(stderr, "kernel_launch: ws too small, need %zu have %zu\n", off, ws_size);
    return;
  }

  const int degOff[6] = {0, 50000, 60000, 110000, 120000, 170000};
  const int sOff[6]   = {0, 10000, 60000, 110000, 120000, 170000};
  const int eOff[6]   = {0, 50000, 100000, 150000, 240000, 340000};
  auto ROWS = [&](int r) { return arena + (size_t)r * 512; };

  auto mkDesc = [](const bf16_t* A, const bf16_t* Bt, const float* bias, void* C,
                   const int* ridx, int N, const int* Nc, int K) {
    GemmDesc d; d.A = A; d.A2 = nullptr; d.Bt = Bt; d.B2 = nullptr;
    d.bias = bias; d.C = C;
    d.ridx = ridx; d.N = N; d.Nc = Nc; d.K = K; d.lda = K; return d;
  };
  GemmDesc dz = mkDesc(nullptr, nullptr, nullptr, nullptr, nullptr, 0, nullptr, 32);

  auto launch_b = [&](GemmDesc a, GemmDesc b, GemmDesc c, GemmDesc d, int nz,
                      int maxN, int M, int acc_) {
    dim3 g(M / 256, (maxN + 127) / 128, nz);
    bgemm<bf16_t><<<g, 512, 0, stream>>>(a, b, c, d, M, acc_);
  };
  auto launch_f = [&](GemmDesc a, GemmDesc b, GemmDesc c, GemmDesc d, int nz,
                      int maxN, int M, int acc_) {
    dim3 g(M / 256, (maxN + 127) / 128, nz);
    bgemm<float><<<g, 512, 0, stream>>>(a, b, c, d, M, acc_);
  };

  // --- weight conversion + af-fold (prologue) ---
  convert_wT24<<<dim3(16, 16, 24), 256, 0, stream>>>(conv_Wl, wl, conv_Wr, wr);
  convert_wT3<<<dim3(16, 12, 3), 256, 0, stream>>>(qp_W, tp_W, ap_W, wqp, wtp, wap);
  convert_wT4h<<<dim3(8, 16, 4), 256, 0, stream>>>(qh_W, rh_W, wqh, wrh0);
  combine_bias6<<<(6 * 512 + 255) / 256, 256, 0, stream>>>(conv_bias, bcAll);
  cast_flat<<<(64 * 512 / 4 + 255) / 256, 256, 0, stream>>>(afp_W2, a2b, 64 * 512 / 4);
  launch_f(mkDesc(a2b, wrh2, nullptr, wfoldF, nullptr, 64, nullptr, 512),
           dz, dz, dz, 1, 64, 256, 0);                      // Wfold = W2 @ rh2
  convert_wT<<<dim3(8, 2, 1), 256, 0, stream>>>(wfoldF, wfoldT, 64, 256);
  fold_cvec<<<1, 256, 0, stream>>>(afp_b2, rh_W + 1024 * 256, cvec);

  // --- fused CSR build + both-side compaction ---
  build_sim<<<(E_SIM + NQ + 255) / 256, 256, 0, stream>>>(ei_sim, simsrc, simdst);
  const int* dsts[6]  = {ei_gr + E_GR, ei_gr, ei_lt, simdst,
                         ei_comp + E_COMP, ei_lt + E_LT};
  const int* srcsA[6] = {ei_gr, ei_gr + E_GR, ei_lt + E_LT, simsrc,
                         ei_comp, ei_lt};
  hipMemsetAsync(degAll, 0, (size_t)(sdegAll + NSTOT) - (size_t)degAll, stream);
  hist6<<<(ETOT + 255) / 256, 256, 0, stream>>>(
      dsts[0], dsts[1], dsts[2], dsts[3], dsts[4], dsts[5],
      srcsA[0], srcsA[1], srcsA[2], srcsA[3], srcsA[4], srcsA[5],
      degAll, sdegAll, posb);
  scan1All<<<648, 256, 0, stream>>>(degAll, sdegAll, startAll, cposAll,
                                    sposAll, bsumAll);
  scan2All<<<18, 64, 0, stream>>>(bsumAll, ccount, scount);
  scan3All<<<(3 * NDTOT + 255) / 256, 256, 0, stream>>>(startAll, cposAll,
                                                        sposAll, bsumAll);
  scatter6<<<(ETOT + 255) / 256, 256, 0, stream>>>(
      dsts[0], dsts[1], dsts[2], dsts[3], dsts[4], dsts[5],
      srcsA[0], srcsA[1], srcsA[2], srcsA[3], srcsA[4], srcsA[5],
      startAll, posb, sposAll, eidxAll, srcCAll);
  compactBoth<<<(NDTOT + NSTOT + 255) / 256, 256, 0, stream>>>(
      degAll, cposAll, cidxAll, sdegAll, sposAll, sidxAll);

  // Input projections: ONE cast + ONE z=3 GEMM dispatch.
  cast3<<<((long)(N4_XQ + N4_XT + N4_XA) + 255) / 256, 256, 0, stream>>>(
      xq, xt, xa, accq, xlb, xrb);
  launch_b(mkDesc(accq, wqp, qp_b, hq, nullptr, NQ, nullptr, 384),
           mkDesc(xlb, wtp, tp_b, ht, nullptr, NT, nullptr, 384),
           mkDesc(xrb, wap, ap_b, ha, nullptr, NA, nullptr, 384),
           dz, 3, NT, 512, 0);

  // Layer loop: 4 GEMM dispatches/layer via relation merging.
  // Arena caps (hard bounds: xr<=min(Nd,E/2), xl<=min(Ns,E)):
  //  A {gr,rgr}: gr-xl@0(10k) gr-xr@10k(25k) rgr-xl@35k(50k) rgr-xr@85k(10k)
  //  B {rlt,sim}: rlt-xl@0(50k) rlt-xr@50k(25k) sim-xl@75k(10k) sim-xr@85k(10k)
  //  C {comp}: xl@0(50k) xr@50k(50k);  D {lt}: xl@0(50k) xr@50k(25k)
  bf16_t *hq_i = hq, *ht_i = ht, *hq_o = accq, *ht_o = acct;
  for (int l = 0; l < 2; ++l) {
    const float* bc_t = bcAll + (size_t)(l * 3 + 0) * 512;
    const float* bc_q = bcAll + (size_t)(l * 3 + 1) * 512;
    const float* bc_a = bcAll + (size_t)(l * 3 + 2) * 512;
    size_t p0 = (size_t)l * 6 + 0;   // gr
    size_t p1 = (size_t)l * 6 + 1;   // rgr
    size_t p3 = (size_t)l * 6 + 3;   // rlt
    size_t p4 = (size_t)l * 6 + 4;   // sim
    size_t p5 = (size_t)l * 6 + 5;   // comp
    size_t p2 = (size_t)l * 6 + 2;   // lt

    auto gat = [&](int r, const bf16_t* xl_, const bf16_t* xr_, size_t po,
                   bf16_t* acc_, int Nd_, int accum, const float* bc, float inv) {
      gat_fused<<<(Nd_ + 3) / 4, 256, 0, stream>>>(
          xl_, xr_, srcCAll + eOff[r], startAll + degOff[r], degAll + degOff[r],
          eidxAll + eOff[r], cposAll + degOff[r], conv_att + po * 512,
          acc_, Nd_, accum, bc, inv);
    };

    // Group A: gr + rgr (z=4)
    launch_b(mkDesc(hq_i, wl + p0 * 262144, conv_bl + p0 * 512, ROWS(0),
                    sidxAll + sOff[0], 10000, scount + 0, 512),
             mkDesc(ht_i, wr + p0 * 262144, conv_br + p0 * 512, ROWS(10000),
                    cidxAll + degOff[0], 25000, ccount + 0, 512),
             mkDesc(ht_i, wl + p1 * 262144, conv_bl + p1 * 512, ROWS(35000),
                    sidxAll + sOff[1], 50000, scount + 1, 512),
             mkDesc(hq_i, wr + p1 * 262144, conv_br + p1 * 512, ROWS(85000),
                    cidxAll + degOff[1], 10000, ccount + 1, 512),
             4, 50000, 512, 0);
    gat(0, ROWS(0), ROWS(10000), p0, ht_o, NT, 0, nullptr, 0.f);      // gr
    gat(1, ROWS(35000), ROWS(85000), p1, hq_o, NQ, 0, nullptr, 0.f);  // rgr

    // Group B: rlt + sim (z=4)
    launch_b(mkDesc(ha, wl + p3 * 262144, conv_bl + p3 * 512, ROWS(0),
                    sidxAll + sOff[2], 50000, scount + 2, 512),
             mkDesc(ht_i, wr + p3 * 262144, conv_br + p3 * 512, ROWS(50000),
                    cidxAll + degOff[2], 25000, ccount + 2, 512),
             mkDesc(hq_i, wl + p4 * 262144, conv_bl + p4 * 512, ROWS(75000),
                    sidxAll + sOff[3], 10000, scount + 3, 512),
             mkDesc(hq_i, wr + p4 * 262144, conv_br + p4 * 512, ROWS(85000),
                    cidxAll + degOff[3], 10000, ccount + 3, 512),
             4, 50000, 512, 0);
    gat(2, ROWS(0), ROWS(50000), p3, ht_o, NT, 1, nullptr, 0.f);      // rlt
    gat(3, ROWS(75000), ROWS(85000), p4, hq_o, NQ, 1, bc_q, 0.5f);    // sim

    // Group C: comp (z=2)
    launch_b(mkDesc(ht_i, wl + p5 * 262144, conv_bl + p5 * 512, ROWS(0),
                    sidxAll + sOff[4], 50000, scount + 4, 512),
             mkDesc(ht_i, wr + p5 * 262144, conv_br + p5 * 512, ROWS(50000),
                    cidxAll + degOff[4], 50000, ccount + 4, 512),
             dz, dz, 2, 50000, 512, 0);
    gat(4, ROWS(0), ROWS(50000), p5, ht_o, NT, 1, bc_t, 1.f / 3.f);   // comp

    // Group D: lt (z=2)
    launch_b(mkDesc(ht_i, wl + p2 * 262144, conv_bl + p2 * 512, ROWS(0),
                    sidxAll + sOff[5], 50000, scount + 5, 512),
             mkDesc(ha, wr + p2 * 262144, conv_br + p2 * 512, ROWS(50000),
                    cidxAll + degOff[5], 25000, ccount + 5, 512),
             dz, dz, 2, 50000, 512, 0);
    gat(5, ROWS(0), ROWS(50000), p2, ha, NA, 0, bc_a, 1.f);           // lt

    bf16_t* t;
    t = hq_i; hq_i = hq_o; hq_o = t;
    t = ht_i; ht_i = ht_o; ht_o = t;
  }
  // after 2 swaps: hq_i==hq, ht_i==ht; acct/accq free.

  // Head (node-space + folded af path), ONE z=3 dispatch {qn, rn, afr}.
  // rn slice uses K-concat: rn = ht@rh0 + ha@rh1 + rh_b in a single K=1024
  // pass (A2/B2 switch at k=512; lda=512 for all four operands).
  float* qn  = (float*)accq;
  float* rn  = (float*)acct;
  float* afr = (float*)xrb;
  bf16_t* afh = xlb;
  const int* gsrc = ei_gen;
  const int* gdst = ei_gen + E_GEN;

  af_hidden<<<(E_GEN * 64 + 255) / 256, 256, 0, stream>>>(af, afp_W1, afp_b1,
                                                          afh, E_GEN);
  GemmDesc dq = mkDesc(hq_i, wqh, qh_b, qn, nullptr, NQ, nullptr, 512);
  GemmDesc dr = mkDesc(ht_i, wrh0, rh_b, rn, nullptr, NT, nullptr, 1024);
  dr.A2 = ha; dr.B2 = wrh1; dr.lda = 512;
  GemmDesc da = mkDesc(afh, wfoldT, nullptr, afr, nullptr, E_GEN, nullptr, 64);
  launch_f(dq, dr, da, dz, 3, NT, 256, 0);
  head_final<<<(E_GEN + 3) / 4, 256, 0, stream>>>(
      qn, rn, afr, cvec, gsrc, gdst,
      qh_g, qh_beta, rh_g, rh_beta, score_b, (float*)d_out, E_GEN);
}